// Round 1
// baseline (240.761 us; speedup 1.0000x reference)
//
#include <hip/hip_runtime.h>
#include <stdint.h>

typedef unsigned short u16;
typedef __bf16 bf16x8 __attribute__((ext_vector_type(8)));
typedef short  short8 __attribute__((ext_vector_type(8)));
typedef float  f32x4  __attribute__((ext_vector_type(4)));
typedef float  float4v __attribute__((ext_vector_type(4)));

#define NG    32
#define NPG   512
#define HIDD  512
#define NH    8
#define HD    64
#define NE    262144
#define NNODE (NG*NPG)

__device__ __forceinline__ u16 f2bf(float f) {
  union { float f; uint32_t u; } x; x.f = f;
  uint32_t r = x.u + 0x7FFFu + ((x.u >> 16) & 1u);
  return (u16)(r >> 16);
}
__device__ __forceinline__ float bf2f(u16 b) {
  union { uint32_t u; float f; } x; x.u = ((uint32_t)b) << 16;
  return x.f;
}
__device__ __forceinline__ bf16x8 ldfrag(const u16* p) {
  short8 t = *(const short8*)p;
  return __builtin_bit_cast(bf16x8, t);
}
__device__ __forceinline__ f32x4 mfma16(bf16x8 a, bf16x8 b, f32x4 c) {
  return __builtin_amdgcn_mfma_f32_16x16x32_bf16(a, b, c, 0, 0, 0);
}
__device__ __forceinline__ void gl2lds16(const void* g, void* l) {
  __builtin_amdgcn_global_load_lds((const __attribute__((address_space(1))) void*)g,
                                   (__attribute__((address_space(3))) void*)l, 16, 0, 0);
}
__device__ __forceinline__ void st(u16* p, float v)   { *p = f2bf(v); }
__device__ __forceinline__ void st(float* p, float v) { *p = v; }

// ---------------- prep kernels ----------------

__global__ void k_cast_x(const float* __restrict__ x, u16* __restrict__ xb) {
  size_t i = ((size_t)blockIdx.x * 256 + threadIdx.x) * 8;
  float4v v0 = *(const float4v*)(x + i);
  float4v v1 = *(const float4v*)(x + i + 4);
  short8 r;
  r[0]=(short)f2bf(v0[0]); r[1]=(short)f2bf(v0[1]); r[2]=(short)f2bf(v0[2]); r[3]=(short)f2bf(v0[3]);
  r[4]=(short)f2bf(v1[0]); r[5]=(short)f2bf(v1[1]); r[6]=(short)f2bf(v1[2]); r[7]=(short)f2bf(v1[3]);
  *(short8*)(xb + i) = r;
}

// wt[z][n][k] = W_z[k][n]  (bf16, n-major so GEMM B-frags are contiguous)
__global__ void k_transw(const float* __restrict__ W0, const float* __restrict__ W1,
                         const float* __restrict__ W2, const float* __restrict__ W3,
                         u16* __restrict__ wt) {
  const float* W = blockIdx.z==0 ? W0 : blockIdx.z==1 ? W1 : blockIdx.z==2 ? W2 : W3;
  u16* out = wt + (size_t)blockIdx.z * HIDD * HIDD;
  __shared__ float tl[32][33];
  int tx = threadIdx.x, ty = threadIdx.y;
  int x0 = blockIdx.x * 32, y0 = blockIdx.y * 32;
  #pragma unroll
  for (int i = 0; i < 4; ++i) tl[ty + i*8][tx] = W[(size_t)(y0 + ty + i*8) * HIDD + x0 + tx];
  __syncthreads();
  #pragma unroll
  for (int i = 0; i < 4; ++i) out[(size_t)(x0 + ty + i*8) * HIDD + (y0 + tx)] = f2bf(tl[tx][ty + i*8]);
}

// eb[e][h] = edge_attr[e] @ We + be ; counts[src]++
__global__ void k_edge_prep(const int* __restrict__ ei, const float* __restrict__ ea,
                            const float* __restrict__ We, const float* __restrict__ be,
                            float* __restrict__ eb, int* __restrict__ counts) {
  __shared__ float w[128];
  __shared__ float bb[8];
  int t = threadIdx.x;
  if (t < 128) w[t] = We[t];
  if (t < 8)   bb[t] = be[t];
  __syncthreads();
  int e = blockIdx.x * 256 + t;
  const float* ap = ea + (size_t)e * 16;
  float a[16];
  #pragma unroll
  for (int i = 0; i < 16; i += 4) {
    float4v v = *(const float4v*)(ap + i);
    a[i]=v[0]; a[i+1]=v[1]; a[i+2]=v[2]; a[i+3]=v[3];
  }
  float acc[8];
  #pragma unroll
  for (int hh = 0; hh < 8; ++hh) acc[hh] = bb[hh];
  #pragma unroll
  for (int d = 0; d < 16; ++d)
    #pragma unroll
    for (int hh = 0; hh < 8; ++hh) acc[hh] += a[d] * w[d*8 + hh];
  #pragma unroll
  for (int hh = 0; hh < 8; ++hh) eb[(size_t)e*8 + hh] = acc[hh];
  atomicAdd(&counts[ei[e]], 1);
}

// exclusive scan of counts[16384] -> rowstart[16385]; single block of 1024
__global__ void k_scan(const int* __restrict__ counts, int* __restrict__ rowstart) {
  __shared__ int arr[1024];
  int t = threadIdx.x;
  int c[16]; int s = 0;
  #pragma unroll
  for (int i = 0; i < 16; ++i) { c[i] = counts[t*16 + i]; s += c[i]; }
  arr[t] = s;
  __syncthreads();
  for (int off = 1; off < 1024; off <<= 1) {
    int v = (t >= off) ? arr[t - off] : 0;
    __syncthreads();
    arr[t] += v;
    __syncthreads();
  }
  int start = arr[t] - s;
  #pragma unroll
  for (int i = 0; i < 16; ++i) { rowstart[t*16 + i] = start; start += c[i]; }
  if (t == 1023) rowstart[16384] = start;
}

// slots[rowstart[src]+pos] = (e<<9)|dst_local
__global__ void k_fill(const int* __restrict__ ei, const int* __restrict__ rowstart,
                       int* __restrict__ cursor, unsigned int* __restrict__ slots) {
  int e = blockIdx.x * 256 + threadIdx.x;
  int src = ei[e];
  int dst = ei[NE + e];
  int pos = atomicAdd(&cursor[src], 1);
  slots[rowstart[src] + pos] = ((unsigned)e << 9) | (unsigned)(dst & (NPG - 1));
}

// ---------------- GEMM (m97-style 128x128, BK=32) ----------------
// A [M,512] bf16 row-major, Bt [512,512] bf16 = W^T (n-major), C [M,512]

template <typename OT>
__device__ void gemm_body(const u16* __restrict__ A, const u16* __restrict__ Bt,
                          const float* __restrict__ bias, OT* __restrict__ C) {
  __shared__ u16 Al[128 * 32];
  __shared__ u16 Bl[128 * 32];
  const int tid = threadIdx.x;
  const int w = tid >> 6, l = tid & 63, lr = l & 15, lg = l >> 4;
  const int bm0 = blockIdx.y * 128, bn0 = blockIdx.x * 128;
  const int wr = w >> 1, wc = w & 1;
  f32x4 acc[4][4];
  #pragma unroll
  for (int i = 0; i < 4; ++i)
    #pragma unroll
    for (int j = 0; j < 4; ++j) acc[i][j] = (f32x4){0.f, 0.f, 0.f, 0.f};

  const int o1 = w * 1024 + l * 16;
  for (int kt = 0; kt < 16; ++kt) {
    #pragma unroll
    for (int rnd = 0; rnd < 2; ++rnd) {
      const int o = rnd * 4096 + o1;
      const int row = o >> 6, colb = o & 63;
      gl2lds16((const char*)A  + ((size_t)(bm0 + row) * HIDD + kt * 32) * 2 + colb,
               (char*)Al + rnd * 4096 + w * 1024);
      gl2lds16((const char*)Bt + ((size_t)(bn0 + row) * HIDD + kt * 32) * 2 + colb,
               (char*)Bl + rnd * 4096 + w * 1024);
    }
    asm volatile("s_waitcnt vmcnt(0)" ::: "memory");
    __syncthreads();
    bf16x8 af[4], bfr[4];
    #pragma unroll
    for (int i = 0; i < 4; ++i) af[i]  = ldfrag(&Al[(wr*64 + i*16 + lr) * 32 + lg*8]);
    #pragma unroll
    for (int j = 0; j < 4; ++j) bfr[j] = ldfrag(&Bl[(wc*64 + j*16 + lr) * 32 + lg*8]);
    #pragma unroll
    for (int i = 0; i < 4; ++i)
      #pragma unroll
      for (int j = 0; j < 4; ++j)
        acc[i][j] = mfma16(af[i], bfr[j], acc[i][j]);
    __syncthreads();
  }
  #pragma unroll
  for (int j = 0; j < 4; ++j) {
    const int col = bn0 + wc*64 + j*16 + lr;
    const float bv = bias[col];
    #pragma unroll
    for (int i = 0; i < 4; ++i) {
      const int row0 = bm0 + wr*64 + i*16 + lg*4;
      #pragma unroll
      for (int q = 0; q < 4; ++q)
        st(&C[(size_t)(row0 + q) * HIDD + col], acc[i][j][q] + bv);
    }
  }
}

__global__ __launch_bounds__(256, 3) void k_gemm_qkv(
    const u16* __restrict__ A, const u16* __restrict__ Wt,
    const float* __restrict__ b0, const float* __restrict__ b1, const float* __restrict__ b2,
    u16* __restrict__ O0, u16* __restrict__ O1, u16* __restrict__ O2) {
  int z = blockIdx.z;
  const u16* Bt = Wt + (size_t)z * HIDD * HIDD;
  const float* bias = (z == 0) ? b0 : (z == 1 ? b1 : b2);
  u16* C = (z == 0) ? O0 : (z == 1 ? O1 : O2);
  gemm_body<u16>(A, Bt, bias, C);
}

__global__ __launch_bounds__(256, 3) void k_gemm_out(
    const u16* __restrict__ A, const u16* __restrict__ Bt,
    const float* __restrict__ bias, float* __restrict__ C) {
  gemm_body<float>(A, Bt, bias, C);
}

// ---------------- fused attention ----------------
// grid: x = 8 q-blocks of 64 rows, y = 8 heads, z = 32 graphs; 256 threads (4 waves)
// Edge bias applied multiplicatively after exp: softmax(S+b) == exp(S-m)*exp(b)/sum.

__global__ __launch_bounds__(256, 2) void k_attn(
    const u16* __restrict__ qb, const u16* __restrict__ kb, const u16* __restrict__ vb,
    const float* __restrict__ eb, const int* __restrict__ rowstart,
    const unsigned int* __restrict__ slots, u16* __restrict__ ab) {
  __shared__ u16 kv[64 * 64];      // 8KB: K tile (swizzled rows) then V^T tile (swizzled)
  __shared__ u16 pl[64 * 512];     // 64KB: P bf16, row-swizzled
  __shared__ float red[256 + 64];  // partial row sums + inv
  const int tid = threadIdx.x, w = tid >> 6, l = tid & 63, lr = l & 15, lg = l >> 4;
  const int b = blockIdx.z, h = blockIdx.y, q0 = blockIdx.x * 64;

  // Q fragments from global (rows w*16+lr of this q-block)
  bf16x8 qf[2];
  {
    int node = b * NPG + q0 + w * 16 + lr;
    const u16* qp = qb + (size_t)node * HIDD + h * HD + lg * 8;
    qf[0] = ldfrag(qp);
    qf[1] = ldfrag(qp + 32);
  }

  // ---- S = Q K^T (raw, unscaled) ----
  f32x4 sacc[32];
  #pragma unroll
  for (int t = 0; t < 32; ++t) sacc[t] = (f32x4){0.f, 0.f, 0.f, 0.f};

  #pragma unroll
  for (int kt = 0; kt < 8; ++kt) {
    #pragma unroll
    for (int rnd = 0; rnd < 2; ++rnd) {
      int o = rnd * 4096 + w * 1024 + l * 16;
      int key = o >> 7, db = o & 127;
      int col = db ^ ((key & 7) << 4);  // pre-swizzled source -> linear LDS dest
      gl2lds16((const char*)kb + ((size_t)(b * NPG + kt * 64 + key) * HIDD + h * HD) * 2 + col,
               (char*)kv + rnd * 4096 + w * 1024);
    }
    asm volatile("s_waitcnt vmcnt(0)" ::: "memory");
    __syncthreads();
    #pragma unroll
    for (int ct = 0; ct < 4; ++ct) {
      int key = ct * 16 + lr;
      #pragma unroll
      for (int ks = 0; ks < 2; ++ks) {
        int db = ((ks * 32 + lg * 8) * 2) ^ ((key & 7) << 4);
        bf16x8 kf = ldfrag(&kv[(key * 128 + db) >> 1]);
        sacc[kt * 4 + ct] = mfma16(qf[ks], kf, sacc[kt * 4 + ct]);
      }
    }
    __syncthreads();
  }

  // ---- row max (wave-local: rows live in this wave's 16-lane groups) ----
  const float scale = 0.125f;  // 1/sqrt(64)
  float mx[4];
  #pragma unroll
  for (int q = 0; q < 4; ++q) {
    float m = -1e30f;
    #pragma unroll
    for (int t = 0; t < 32; ++t) m = fmaxf(m, sacc[t][q]);
    #pragma unroll
    for (int s = 1; s < 16; s <<= 1) m = fmaxf(m, __shfl_xor(m, s, 64));
    mx[q] = m * scale;
  }

  // ---- P = exp(S*scale - mx) -> LDS bf16 (row-swizzled) ----
  #pragma unroll
  for (int t = 0; t < 32; ++t) {
    #pragma unroll
    for (int q = 0; q < 4; ++q) {
      int row = w * 16 + lg * 4 + q;
      int colb = ((t * 16 + lr) * 2) ^ ((row & 7) << 4);
      float pv = __expf(sacc[t][q] * scale - mx[q]);
      pl[(row * 1024 + colb) >> 1] = f2bf(pv);
    }
  }
  __syncthreads();

  // ---- edge bias: P[r][dst] *= exp(eb[e][h]); one thread owns one row ----
  if (tid < 64) {
    int r = tid;
    int grow = b * NPG + q0 + r;
    int s0 = rowstart[grow], s1 = rowstart[grow + 1];
    int swz = (r & 7) << 4;
    for (int s = s0; s < s1; ++s) {
      unsigned int u = slots[s];
      int dst = (int)(u & (NPG - 1));
      int eid = (int)(u >> 9);
      float mfac = __expf(eb[(size_t)eid * 8 + h]);
      int idx = (r * 1024 + ((dst * 2) ^ swz)) >> 1;
      pl[idx] = f2bf(bf2f(pl[idx]) * mfac);
    }
  }
  __syncthreads();

  // ---- row sums ----
  {
    int r = tid & 63, qt = tid >> 6;
    float s = 0.f;
    int swz = (r & 7) << 4;
    #pragma unroll
    for (int i = 0; i < 16; ++i) {
      int colb = (qt * 256 + i * 16) ^ swz;
      short8 v = *(const short8*)&pl[(r * 1024 + colb) >> 1];
      #pragma unroll
      for (int j = 0; j < 8; ++j) s += bf2f((u16)v[j]);
    }
    red[qt * 64 + r] = s;
  }
  __syncthreads();
  if (tid < 64) {
    float s = red[tid] + red[64 + tid] + red[128 + tid] + red[192 + tid];
    red[256 + tid] = 1.0f / s;
  }
  __syncthreads();

  // ---- O = P V ----
  f32x4 oacc[4];
  #pragma unroll
  for (int dt = 0; dt < 4; ++dt) oacc[dt] = (f32x4){0.f, 0.f, 0.f, 0.f};

  #pragma unroll
  for (int vt = 0; vt < 8; ++vt) {
    // stage V^T tile [64 d][64 keys], swizzled by ((d&7)<<4)
    #pragma unroll
    for (int rnd = 0; rnd < 2; ++rnd) {
      int idx = rnd * 256 + tid;
      int d8 = idx & 7, key = idx >> 3;
      const u16* src = vb + (size_t)(b * NPG + vt * 64 + key) * HIDD + h * HD + d8 * 8;
      short8 v = *(const short8*)src;
      #pragma unroll
      for (int j = 0; j < 8; ++j) {
        int d = d8 * 8 + j;
        int byteo = d * 128 + ((key * 2) ^ ((d & 7) << 4));
        kv[byteo >> 1] = (u16)v[j];
      }
    }
    __syncthreads();
    #pragma unroll
    for (int ks = 0; ks < 2; ++ks) {
      int prow = w * 16 + lr;
      int pcolb = ((vt * 64 + ks * 32 + lg * 8) * 2) ^ ((prow & 7) << 4);
      bf16x8 pa = ldfrag(&pl[(prow * 1024 + pcolb) >> 1]);
      #pragma unroll
      for (int dt = 0; dt < 4; ++dt) {
        int d = dt * 16 + lr;
        int vcolb = ((ks * 32 + lg * 8) * 2) ^ ((d & 7) << 4);
        bf16x8 vf = ldfrag(&kv[(d * 128 + vcolb) >> 1]);
        oacc[dt] = mfma16(pa, vf, oacc[dt]);
      }
    }
    __syncthreads();
  }

  // ---- normalize + store bf16 ----
  #pragma unroll
  for (int dt = 0; dt < 4; ++dt) {
    #pragma unroll
    for (int q = 0; q < 4; ++q) {
      int row = w * 16 + lg * 4 + q;
      float v = oacc[dt][q] * red[256 + row];
      int node = b * NPG + q0 + row;
      ab[(size_t)node * HIDD + h * HD + dt * 16 + lr] = f2bf(v);
    }
  }
}

// ---------------- launch ----------------

extern "C" void kernel_launch(void* const* d_in, const int* in_sizes, int n_in,
                              void* d_out, int out_size, void* d_ws, size_t ws_size,
                              hipStream_t stream) {
  const float* x  = (const float*)d_in[0];
  const int*   ei = (const int*)d_in[2];
  const float* ea = (const float*)d_in[3];
  const float* Wq = (const float*)d_in[4];  const float* bq = (const float*)d_in[5];
  const float* Wk = (const float*)d_in[6];  const float* bk = (const float*)d_in[7];
  const float* Wv = (const float*)d_in[8];  const float* bv = (const float*)d_in[9];
  const float* Wo = (const float*)d_in[10]; const float* bo = (const float*)d_in[11];
  const float* We = (const float*)d_in[12]; const float* be = (const float*)d_in[13];

  char* ws = (char*)d_ws;
  const size_t MB = 1 << 20;
  u16*  xb  = (u16*)(ws);             // 16 MiB  (aliased as ab after QKV GEMM)
  u16*  wt  = (u16*)(ws + 16*MB);     // 2 MiB   (Wq,Wk,Wv,Wo transposed bf16)
  u16*  qbp = (u16*)(ws + 18*MB);     // 16 MiB
  u16*  kbp = (u16*)(ws + 34*MB);     // 16 MiB
  u16*  vbp = (u16*)(ws + 50*MB);     // 16 MiB
  float* ebp = (float*)(ws + 66*MB);  // 8 MiB
  int*  counts  = (int*)(ws + 74*MB);            // 64 KiB
  int*  cursor  = (int*)(ws + 74*MB + 65536);    // 64 KiB
  int*  rowstart= (int*)(ws + 74*MB + 2*65536);  // 128 KiB region
  unsigned int* slots = (unsigned int*)(ws + 74*MB + 4*65536);  // 1 MiB
  u16*  ab = xb;  // alias: x_bf16 dead after QKV GEMM

  hipMemsetAsync(counts, 0, 2 * 65536, stream);  // counts + cursor

  k_cast_x<<<dim3(NNODE * HIDD / (256 * 8)), 256, 0, stream>>>(x, xb);
  k_transw<<<dim3(16, 16, 4), dim3(32, 8, 1), 0, stream>>>(Wq, Wk, Wv, Wo, wt);
  k_edge_prep<<<dim3(NE / 256), 256, 0, stream>>>(ei, ea, We, be, ebp, counts);
  k_scan<<<1, 1024, 0, stream>>>(counts, rowstart);
  k_fill<<<dim3(NE / 256), 256, 0, stream>>>(ei, rowstart, cursor, slots);

  k_gemm_qkv<<<dim3(HIDD / 128, NNODE / 128, 3), 256, 0, stream>>>(
      xb, wt, bq, bk, bv, qbp, kbp, vbp);

  k_attn<<<dim3(8, NH, NG), 256, 0, stream>>>(qbp, kbp, vbp, ebp, rowstart, slots, ab);

  k_gemm_out<<<dim3(HIDD / 128, NNODE / 128, 1), 256, 0, stream>>>(
      ab, wt + (size_t)3 * HIDD * HIDD, bo, (float*)d_out);
}

// Round 2
// 198.750 us; speedup vs baseline: 1.2114x; 1.2114x over previous
//
#include <hip/hip_runtime.h>
#include <stdint.h>

typedef unsigned short u16;
typedef __bf16 bf16x8 __attribute__((ext_vector_type(8)));
typedef short  short8 __attribute__((ext_vector_type(8)));
typedef float  f32x4  __attribute__((ext_vector_type(4)));
typedef float  float4v __attribute__((ext_vector_type(4)));

#define NG    32
#define NPG   512
#define HIDD  512
#define NH    8
#define HD    64
#define NE    262144
#define NNODE (NG*NPG)

__device__ __forceinline__ u16 f2bf(float f) {
  union { float f; uint32_t u; } x; x.f = f;
  uint32_t r = x.u + 0x7FFFu + ((x.u >> 16) & 1u);
  return (u16)(r >> 16);
}
__device__ __forceinline__ float bf2f(u16 b) {
  union { uint32_t u; float f; } x; x.u = ((uint32_t)b) << 16;
  return x.f;
}
__device__ __forceinline__ bf16x8 ldfrag(const u16* p) {
  short8 t = *(const short8*)p;
  return __builtin_bit_cast(bf16x8, t);
}
__device__ __forceinline__ f32x4 mfma16(bf16x8 a, bf16x8 b, f32x4 c) {
  return __builtin_amdgcn_mfma_f32_16x16x32_bf16(a, b, c, 0, 0, 0);
}
__device__ __forceinline__ void gl2lds16(const void* g, void* l) {
  __builtin_amdgcn_global_load_lds((const __attribute__((address_space(1))) void*)g,
                                   (__attribute__((address_space(3))) void*)l, 16, 0, 0);
}
__device__ __forceinline__ void st(u16* p, float v)   { *p = f2bf(v); }
__device__ __forceinline__ void st(float* p, float v) { *p = v; }

// ---------------- prep kernels ----------------

__global__ void k_cast_x(const float* __restrict__ x, u16* __restrict__ xb) {
  size_t i = ((size_t)blockIdx.x * 256 + threadIdx.x) * 8;
  float4v v0 = *(const float4v*)(x + i);
  float4v v1 = *(const float4v*)(x + i + 4);
  short8 r;
  r[0]=(short)f2bf(v0[0]); r[1]=(short)f2bf(v0[1]); r[2]=(short)f2bf(v0[2]); r[3]=(short)f2bf(v0[3]);
  r[4]=(short)f2bf(v1[0]); r[5]=(short)f2bf(v1[1]); r[6]=(short)f2bf(v1[2]); r[7]=(short)f2bf(v1[3]);
  *(short8*)(xb + i) = r;
}

// wt[z][n][k] = W_z[k][n]  (bf16, n-major so GEMM B-frags are contiguous)
__global__ void k_transw(const float* __restrict__ W0, const float* __restrict__ W1,
                         const float* __restrict__ W2, const float* __restrict__ W3,
                         u16* __restrict__ wt) {
  const float* W = blockIdx.z==0 ? W0 : blockIdx.z==1 ? W1 : blockIdx.z==2 ? W2 : W3;
  u16* out = wt + (size_t)blockIdx.z * HIDD * HIDD;
  __shared__ float tl[32][33];
  int tx = threadIdx.x, ty = threadIdx.y;
  int x0 = blockIdx.x * 32, y0 = blockIdx.y * 32;
  #pragma unroll
  for (int i = 0; i < 4; ++i) tl[ty + i*8][tx] = W[(size_t)(y0 + ty + i*8) * HIDD + x0 + tx];
  __syncthreads();
  #pragma unroll
  for (int i = 0; i < 4; ++i) out[(size_t)(x0 + ty + i*8) * HIDD + (y0 + tx)] = f2bf(tl[tx][ty + i*8]);
}

__global__ void k_count(const int* __restrict__ ei, int* __restrict__ counts) {
  int e = blockIdx.x * 256 + threadIdx.x;
  atomicAdd(&counts[ei[e]], 1);
}

// exclusive scan of counts[16384] -> rowstart[16385]; single block of 1024
__global__ void k_scan(const int* __restrict__ counts, int* __restrict__ rowstart) {
  __shared__ int arr[1024];
  int t = threadIdx.x;
  int c[16]; int s = 0;
  #pragma unroll
  for (int i = 0; i < 16; ++i) { c[i] = counts[t*16 + i]; s += c[i]; }
  arr[t] = s;
  __syncthreads();
  for (int off = 1; off < 1024; off <<= 1) {
    int v = (t >= off) ? arr[t - off] : 0;
    __syncthreads();
    arr[t] += v;
    __syncthreads();
  }
  int start = arr[t] - s;
  #pragma unroll
  for (int i = 0; i < 16; ++i) { rowstart[t*16 + i] = start; start += c[i]; }
  if (t == 1023) rowstart[16384] = start;
}

// packed[(rowstart[src]+pos)*8 + h] = dst | f16(exp(edge_attr@We+be))<<16
__global__ void k_fill(const int* __restrict__ ei, const float* __restrict__ ea,
                       const float* __restrict__ We, const float* __restrict__ be,
                       const int* __restrict__ rowstart, int* __restrict__ cursor,
                       uint32_t* __restrict__ packed) {
  __shared__ float w[128];
  __shared__ float bb[8];
  int t = threadIdx.x;
  if (t < 128) w[t] = We[t];
  if (t < 8)   bb[t] = be[t];
  __syncthreads();
  int e = blockIdx.x * 256 + t;
  int src = ei[e];
  int dst = ei[NE + e];
  const float* ap = ea + (size_t)e * 16;
  float a[16];
  #pragma unroll
  for (int i = 0; i < 16; i += 4) {
    float4v v = *(const float4v*)(ap + i);
    a[i]=v[0]; a[i+1]=v[1]; a[i+2]=v[2]; a[i+3]=v[3];
  }
  float acc[8];
  #pragma unroll
  for (int hh = 0; hh < 8; ++hh) acc[hh] = bb[hh];
  #pragma unroll
  for (int d = 0; d < 16; ++d)
    #pragma unroll
    for (int hh = 0; hh < 8; ++hh) acc[hh] += a[d] * w[d*8 + hh];
  int pos = atomicAdd(&cursor[src], 1);
  size_t base = ((size_t)(rowstart[src] + pos)) * 8;
  #pragma unroll
  for (int hh = 0; hh < 8; ++hh) {
    float m = __expf(acc[hh]);
    union { _Float16 hf; u16 us; } cv; cv.hf = (_Float16)m;
    packed[base + hh] = (uint32_t)(dst & (NPG - 1)) | ((uint32_t)cv.us << 16);
  }
}

// ---------------- GEMM (128x128, BK=32, double-buffered + counted vmcnt) ----------------

template <typename OT>
__device__ void gemm_body(const u16* __restrict__ A, const u16* __restrict__ Bt,
                          const float* __restrict__ bias, OT* __restrict__ C) {
  __shared__ u16 Al[2][4096];
  __shared__ u16 Bl[2][4096];
  const int tid = threadIdx.x;
  const int w = tid >> 6, l = tid & 63, lr = l & 15, lg = l >> 4;
  const int bm0 = blockIdx.y * 128, bn0 = blockIdx.x * 128;
  const int wr = w >> 1, wc = w & 1;
  f32x4 acc[4][4];
  #pragma unroll
  for (int i = 0; i < 4; ++i)
    #pragma unroll
    for (int j = 0; j < 4; ++j) acc[i][j] = (f32x4){0.f, 0.f, 0.f, 0.f};

  const int o1 = w * 1024 + l * 16;
  auto stageAB = [&](int kt, int buf) {
    #pragma unroll
    for (int rnd = 0; rnd < 2; ++rnd) {
      const int o = rnd * 4096 + o1;
      const int row = o >> 6, colb = o & 63;
      gl2lds16((const char*)A  + ((size_t)(bm0 + row) * HIDD + kt * 32) * 2 + colb,
               (char*)&Al[buf][0] + o);
      gl2lds16((const char*)Bt + ((size_t)(bn0 + row) * HIDD + kt * 32) * 2 + colb,
               (char*)&Bl[buf][0] + o);
    }
  };

  stageAB(0, 0);
  for (int kt = 0; kt < 16; ++kt) {
    if (kt < 15) {
      stageAB(kt + 1, (kt + 1) & 1);
      asm volatile("s_waitcnt vmcnt(4)" ::: "memory");
    } else {
      asm volatile("s_waitcnt vmcnt(0)" ::: "memory");
    }
    __syncthreads();
    const u16* Ab = &Al[kt & 1][0];
    const u16* Bb = &Bl[kt & 1][0];
    bf16x8 af[4], bfr[4];
    #pragma unroll
    for (int i = 0; i < 4; ++i) af[i]  = ldfrag(&Ab[(wr*64 + i*16 + lr) * 32 + lg*8]);
    #pragma unroll
    for (int j = 0; j < 4; ++j) bfr[j] = ldfrag(&Bb[(wc*64 + j*16 + lr) * 32 + lg*8]);
    #pragma unroll
    for (int i = 0; i < 4; ++i)
      #pragma unroll
      for (int j = 0; j < 4; ++j)
        acc[i][j] = mfma16(af[i], bfr[j], acc[i][j]);
    __syncthreads();
  }
  #pragma unroll
  for (int j = 0; j < 4; ++j) {
    const int col = bn0 + wc*64 + j*16 + lr;
    const float bv = bias[col];
    #pragma unroll
    for (int i = 0; i < 4; ++i) {
      const int row0 = bm0 + wr*64 + i*16 + lg*4;
      #pragma unroll
      for (int q = 0; q < 4; ++q)
        st(&C[(size_t)(row0 + q) * HIDD + col], acc[i][j][q] + bv);
    }
  }
}

__global__ __launch_bounds__(256, 3) void k_gemm_qkv(
    const u16* __restrict__ A, const u16* __restrict__ Wt,
    const float* __restrict__ b0, const float* __restrict__ b1, const float* __restrict__ b2,
    u16* __restrict__ O0, u16* __restrict__ O1, u16* __restrict__ O2) {
  int z = blockIdx.z;
  const u16* Bt = Wt + (size_t)z * HIDD * HIDD;
  const float* bias = (z == 0) ? b0 : (z == 1 ? b1 : b2);
  u16* C = (z == 0) ? O0 : (z == 1 ? O1 : O2);
  gemm_body<u16>(A, Bt, bias, C);
}

__global__ __launch_bounds__(256, 3) void k_gemm_out(
    const u16* __restrict__ A, const u16* __restrict__ Bt,
    const float* __restrict__ bias, float* __restrict__ C) {
  gemm_body<float>(A, Bt, bias, C);
}

// ---------------- fused attention ----------------
// 2048 blocks (XCD-swizzled), 256 threads (4 waves). Per block: one (graph, head,
// 64-query tile). K triple-buffered in the P region (counted vmcnt), P bf16 in LDS
// (XOR swizzle), edge bias multiplicative via packed (dst, f16 exp) with 4 threads/row,
// row sums in registers + edge deltas, PV with reg-staged V (T14) into swizzled LDS.

__global__ __launch_bounds__(256, 2) void k_attn(
    const u16* __restrict__ qb, const u16* __restrict__ kb, const u16* __restrict__ vb,
    const uint32_t* __restrict__ packed, const int* __restrict__ rowstart,
    u16* __restrict__ ab) {
  __shared__ u16 pl[64 * 512];     // 64KB P; first 3*4096 u16 double as K staging bufs
  __shared__ u16 vbuf[64 * 64];    // 8KB V^T tile
  __shared__ float red[64];        // row sums -> inverses
  const int tid = threadIdx.x, w = tid >> 6, l = tid & 63, lr = l & 15, lg = l >> 4;

  const int id = blockIdx.x;
  const int nid = (id & 7) * 256 + (id >> 3);   // XCD-contiguous chunks (2048 % 8 == 0)
  const int q0 = (nid & 7) * 64;
  const int h  = (nid >> 3) & 7;
  const int b  = nid >> 6;

  // Q fragments (rows w*16+lr of this q-block)
  bf16x8 qf[2];
  {
    int node = b * NPG + q0 + w * 16 + lr;
    const u16* qp = qb + (size_t)node * HIDD + h * HD + lg * 8;
    qf[0] = ldfrag(qp);
    qf[1] = ldfrag(qp + 32);
  }

  auto stageK = [&](int kt, int buf) {
    #pragma unroll
    for (int rnd = 0; rnd < 2; ++rnd) {
      int o = rnd * 4096 + w * 1024 + l * 16;
      int key = o >> 7, db = o & 127;
      int col = db ^ ((key & 7) << 4);  // pre-swizzled source -> linear LDS dest
      gl2lds16((const char*)kb + ((size_t)(b * NPG + kt * 64 + key) * HIDD + h * HD) * 2 + col,
               (char*)pl + buf * 8192 + o);
    }
  };

  // ---- S = Q K^T, 2-deep pipelined K staging ----
  f32x4 sacc[32];
  #pragma unroll
  for (int t = 0; t < 32; ++t) sacc[t] = (f32x4){0.f, 0.f, 0.f, 0.f};

  stageK(0, 0);
  stageK(1, 1);
  #pragma unroll
  for (int kt = 0; kt < 8; ++kt) {
    if (kt < 6) {
      stageK(kt + 2, (kt + 2) % 3);
      asm volatile("s_waitcnt vmcnt(4)" ::: "memory");
    } else if (kt == 6) {
      asm volatile("s_waitcnt vmcnt(2)" ::: "memory");
    } else {
      asm volatile("s_waitcnt vmcnt(0)" ::: "memory");
    }
    __syncthreads();
    const u16* kB = pl + (kt % 3) * 4096;
    #pragma unroll
    for (int ct = 0; ct < 4; ++ct) {
      int key = ct * 16 + lr;
      #pragma unroll
      for (int ks = 0; ks < 2; ++ks) {
        int db = ((ks * 32 + lg * 8) * 2) ^ ((key & 7) << 4);
        bf16x8 kf = ldfrag(&kB[(key * 128 + db) >> 1]);
        sacc[kt * 4 + ct] = mfma16(qf[ks], kf, sacc[kt * 4 + ct]);
      }
    }
    __syncthreads();
  }

  // ---- row max ----
  const float scale = 0.125f;  // 1/sqrt(64)
  float mx[4];
  #pragma unroll
  for (int q = 0; q < 4; ++q) {
    float m = -1e30f;
    #pragma unroll
    for (int t = 0; t < 32; ++t) m = fmaxf(m, sacc[t][q]);
    #pragma unroll
    for (int s = 1; s < 16; s <<= 1) m = fmaxf(m, __shfl_xor(m, s, 64));
    mx[q] = m * scale;
  }

  // V(0) register prefetch — flies through P-write + edge phases
  short8 vA[2], vB[2];
  auto loadV = [&](short8* dr, int vt) {
    #pragma unroll
    for (int rnd = 0; rnd < 2; ++rnd) {
      int idx = rnd * 256 + tid;
      int d8 = idx & 7, key = idx >> 3;
      dr[rnd] = *(const short8*)(vb + (size_t)(b * NPG + vt * 64 + key) * HIDD + h * HD + d8 * 8);
    }
  };
  loadV(vA, 0);

  // ---- P = exp(S*scale - mx) -> LDS bf16; row sums in registers ----
  float rs[4] = {0.f, 0.f, 0.f, 0.f};
  #pragma unroll
  for (int t = 0; t < 32; ++t) {
    #pragma unroll
    for (int q = 0; q < 4; ++q) {
      int row = w * 16 + lg * 4 + q;
      int colb = ((t * 16 + lr) * 2) ^ (((row ^ (row >> 3)) & 7) << 4);
      float pv = __expf(sacc[t][q] * scale - mx[q]);
      u16 pb = f2bf(pv);
      pl[(row * 1024 + colb) >> 1] = pb;
      rs[q] += bf2f(pb);
    }
  }
  #pragma unroll
  for (int q = 0; q < 4; ++q) {
    #pragma unroll
    for (int s = 1; s < 16; s <<= 1) rs[q] += __shfl_xor(rs[q], s, 64);
    if (lr == 0) red[w * 16 + lg * 4 + q] = rs[q];
  }
  __syncthreads();

  // ---- edge multipliers: 4 threads/row, disjoint dst&3 classes (dup-safe) ----
  {
    int r = tid >> 2, c = tid & 3;
    int grow = b * NPG + q0 + r;
    int s0 = rowstart[grow], s1 = rowstart[grow + 1];
    int swzp = ((r ^ (r >> 3)) & 7) << 4;
    float delta = 0.f;
    for (int s = s0; s < s1; ++s) {
      uint32_t u = packed[(size_t)s * 8 + h];
      int dst = (int)(u & 0xFFFFu);
      if ((dst & 3) == c) {
        union { u16 us; _Float16 hf; } cv; cv.us = (u16)(u >> 16);
        float mult = (float)cv.hf;
        int idx = (r * 1024 + ((dst * 2) ^ swzp)) >> 1;
        float old = bf2f(pl[idx]);
        u16 nb = f2bf(old * mult);
        pl[idx] = nb;
        delta += bf2f(nb) - old;
      }
    }
    atomicAdd(&red[r], delta);
  }
  __syncthreads();
  if (tid < 64) red[tid] = 1.0f / red[tid];  // ordered vs readers by PV barriers

  // ---- O = P V, reg-staged V (T14), single LDS buffer ----
  auto writeV = [&](const short8* reg) {
    #pragma unroll
    for (int rnd = 0; rnd < 2; ++rnd) {
      int idx = rnd * 256 + tid;
      int d8 = idx & 7, key = idx >> 3;
      #pragma unroll
      for (int j = 0; j < 8; ++j) {
        int d = d8 * 8 + j;
        int byteo = d * 128 + ((key * 2) ^ (((j ^ d8) & 7) << 4));
        vbuf[byteo >> 1] = (u16)reg[rnd][j];
      }
    }
  };

  f32x4 oacc[4];
  #pragma unroll
  for (int dt = 0; dt < 4; ++dt) oacc[dt] = (f32x4){0.f, 0.f, 0.f, 0.f};

  const int prow = w * 16 + lr;
  const int swzp = ((prow ^ (prow >> 3)) & 7) << 4;

  #pragma unroll
  for (int vt = 0; vt < 8; ++vt) {
    const short8* cur = (vt & 1) ? vB : vA;
    short8* nxt = (vt & 1) ? vA : vB;
    if (vt < 7) loadV(nxt, vt + 1);   // issue early: hides under DS writes + MFMAs
    writeV(cur);
    __syncthreads();
    #pragma unroll
    for (int ks = 0; ks < 2; ++ks) {
      int pcolb = ((vt * 64 + ks * 32 + lg * 8) * 2) ^ swzp;
      bf16x8 pa = ldfrag(&pl[(prow * 1024 + pcolb) >> 1]);
      #pragma unroll
      for (int dt = 0; dt < 4; ++dt) {
        int d = dt * 16 + lr;
        int vcolb = ((ks * 32 + lg * 8) * 2) ^ (((d ^ (d >> 3)) & 7) << 4);
        bf16x8 vf = ldfrag(&vbuf[(d * 128 + vcolb) >> 1]);
        oacc[dt] = mfma16(pa, vf, oacc[dt]);
      }
    }
    __syncthreads();
  }

  // ---- normalize + store bf16 ----
  #pragma unroll
  for (int dt = 0; dt < 4; ++dt) {
    #pragma unroll
    for (int q = 0; q < 4; ++q) {
      int row = w * 16 + lg * 4 + q;
      float v = oacc[dt][q] * red[row];
      int node = b * NPG + q0 + row;
      ab[(size_t)node * HIDD + h * HD + dt * 16 + lr] = f2bf(v);
    }
  }
}

// ---------------- launch ----------------

extern "C" void kernel_launch(void* const* d_in, const int* in_sizes, int n_in,
                              void* d_out, int out_size, void* d_ws, size_t ws_size,
                              hipStream_t stream) {
  const float* x  = (const float*)d_in[0];
  const int*   ei = (const int*)d_in[2];
  const float* ea = (const float*)d_in[3];
  const float* Wq = (const float*)d_in[4];  const float* bq = (const float*)d_in[5];
  const float* Wk = (const float*)d_in[6];  const float* bk = (const float*)d_in[7];
  const float* Wv = (const float*)d_in[8];  const float* bv = (const float*)d_in[9];
  const float* Wo = (const float*)d_in[10]; const float* bo = (const float*)d_in[11];
  const float* We = (const float*)d_in[12]; const float* be = (const float*)d_in[13];

  char* ws = (char*)d_ws;
  const size_t MB = 1 << 20;
  u16*  xb  = (u16*)(ws);             // 16 MiB (aliased as ab after QKV GEMM)
  u16*  wt  = (u16*)(ws + 16*MB);     // 2 MiB
  u16*  qbp = (u16*)(ws + 18*MB);     // 16 MiB
  u16*  kbp = (u16*)(ws + 34*MB);     // 16 MiB
  u16*  vbp = (u16*)(ws + 50*MB);     // 16 MiB
  uint32_t* packed = (uint32_t*)(ws + 66*MB);    // 8 MiB (E*8 u32)
  int*  counts  = (int*)(ws + 74*MB);            // 64 KiB
  int*  cursor  = (int*)(ws + 74*MB + 65536);    // 64 KiB
  int*  rowstart= (int*)(ws + 74*MB + 2*65536);  // 128 KiB region
  u16*  ab = xb;

  hipMemsetAsync(counts, 0, 2 * 65536, stream);  // counts + cursor

  k_cast_x<<<dim3(NNODE * HIDD / (256 * 8)), 256, 0, stream>>>(x, xb);
  k_transw<<<dim3(16, 16, 4), dim3(32, 8, 1), 0, stream>>>(Wq, Wk, Wv, Wo, wt);
  k_count<<<dim3(NE / 256), 256, 0, stream>>>(ei, counts);
  k_scan<<<1, 1024, 0, stream>>>(counts, rowstart);
  k_fill<<<dim3(NE / 256), 256, 0, stream>>>(ei, ea, We, be, rowstart, cursor, packed);

  k_gemm_qkv<<<dim3(HIDD / 128, NNODE / 128, 3), 256, 0, stream>>>(
      xb, wt, bq, bk, bv, qbp, kbp, vbp);

  k_attn<<<dim3(2048), 256, 0, stream>>>(qbp, kbp, vbp, packed, rowstart, ab);

  k_gemm_out<<<dim3(HIDD / 128, NNODE / 128, 1), 256, 0, stream>>>(
      ab, wt + (size_t)3 * HIDD * HIDD, bo, (float*)d_out);
}